// Round 7
// baseline (254.372 us; speedup 1.0000x reference)
//
#include <hip/hip_runtime.h>

#define Dm 96
#define PL (Dm*Dm*Dm)               // 884736 elements per (b, ic) plane
#define ICn 16
#define OCn 16
#define HYPn 128
#define BSn 4
// K-packing: 15 groups of K=32. grp = ty*5 + g (ty = ky tap 0..2, g = 0..4).
// k_local = cl*16 + ic, cl in {0,1} -> (kz,kx) combo c = 2g+cl (c=9 is padding).
// Single ky per group => B-fragment depends only on the INPUT y-plane, shared
// across neighboring output rows.
#define NG 15
#define FRAG_ELEMS (NG*64*8)        // 7680 bf16 per sample

typedef float   f32x4  __attribute__((ext_vector_type(4)));
typedef __bf16  bf16x8 __attribute__((ext_vector_type(8)));

__device__ __forceinline__ unsigned short f2bf(float f) {
    unsigned u = __builtin_bit_cast(unsigned, f);
    u = (u + 0x7FFFu + ((u >> 16) & 1u)) >> 16;
    return (unsigned short)u;
}

// ---------------- hypernetwork: A-fragments in MFMA lane order ----------------
__global__ __launch_bounds__(256)
void hyper_frag_kernel(const float* __restrict__ hyp, const float* __restrict__ Wk,
                       const float* __restrict__ bk, unsigned short* __restrict__ kwf)
{
    int t = blockIdx.x * 256 + threadIdx.x;
    if (t >= BSn * FRAG_ELEMS) return;
    int j    = t & 7;
    int lane = (t >> 3) & 63;
    int rest = t >> 9;
    int grp  = rest % NG;
    int b    = rest / NG;
    int oc = lane & 15, hi = lane >> 4;
    int ty = grp / 5, g = grp % 5;
    int cl = hi >> 1;
    int ic = (hi & 1) * 8 + j;
    int c  = 2 * g + cl;
    float acc = 0.f;
    if (c < 9) {
        int tz = c / 3, tx = c % 3;
        int r = (oc * ICn + ic) * 27 + (tz * 9 + ty * 3 + tx);
        const float4* w = (const float4*)(Wk + (long)r * HYPn);
        const float4* h = (const float4*)(hyp + (long)b * HYPn);
        acc = bk[r];
#pragma unroll
        for (int q = 0; q < HYPn / 4; ++q) {
            float4 a = h[q], cc = w[q];
            acc += a.x * cc.x + a.y * cc.y + a.z * cc.z + a.w * cc.w;
        }
    }
    kwf[t] = f2bf(acc);
}

__global__ __launch_bounds__(64)
void hyper_bias_kernel(const float* __restrict__ hyp, const float* __restrict__ Wb,
                       const float* __restrict__ bb, float* __restrict__ bias)
{
    int t = threadIdx.x;          // 64 = 4 samples * 16 oc
    int b = t >> 4, oc = t & 15;
    const float4* w = (const float4*)(Wb + (long)oc * HYPn);
    const float4* h = (const float4*)(hyp + (long)b * HYPn);
    float acc = bb[oc];
#pragma unroll
    for (int q = 0; q < HYPn / 4; ++q) {
        float4 a = h[q], c = w[q];
        acc += a.x * c.x + a.y * c.y + a.z * c.z + a.w * c.w;
    }
    bias[t] = acc;                // [b][oc]
}

// ---------------- MFMA implicit-GEMM conv: wave-private units ----------------
// One 64-thread block (= 1 wave) = one output tile: 1z x 8y x 16x, 16 oc.
// Private LDS tile [3z][10y][18x] x 32B = 17.3 KB -> 9 blocks/CU, all waves
// independent (no cross-wave barrier => no correlated stage stalls).
#define YT 8
#define XT 16
#define ZL 3
#define YL 10
#define XL 18
#define SPN (ZL*YL*XL)              // 540 spatial points
#define SSTR 32
#define LDSB (SPN*SSTR)             // 17280 bytes

__device__ constexpr int coff(int c) {   // (kz,kx) combo byte offset
    return ((c / 3) * YL * XL + (c % 3)) * SSTR;
}

__device__ __forceinline__ void mask16(bf16x8 &v, unsigned m) {
    uint4 u = __builtin_bit_cast(uint4, v);
    u.x &= m; u.y &= m; u.z &= m; u.w &= m;
    v = __builtin_bit_cast(bf16x8, u);
}

struct IT { f32x4 r[8]; int sp; int ich; unsigned m; bool wr; };
struct HT { float r[8]; int sp; int ich; unsigned m; bool wr; };

__device__ __forceinline__ void issueI(const float* __restrict__ xb, int z, int y0, int x0,
                                       int idx, IT &t) {
    int xq = idx & 3, ich = (idx >> 2) & 1, row = idx >> 3;   // row may be >=30 for tail
    int ly = row % YL, lz = row / YL;
    int gz = z - 1 + lz, gy = y0 - 1 + ly;
    bool ok = ((unsigned)gz < (unsigned)Dm) && ((unsigned)gy < (unsigned)Dm);
    t.m = ok ? 0xFFFFFFFFu : 0u;
    int gzc = ok ? gz : 0, gyc = ok ? gy : 0;
    const float* g = xb + (long)(ich * 8) * PL + ((long)gzc * Dm + gyc) * Dm + (x0 + 4 * xq);
#pragma unroll
    for (int q = 0; q < 8; ++q) t.r[q] = *(const f32x4*)(g + (long)q * PL);
    t.sp = row * XL + 1 + 4 * xq;
    t.ich = ich;
    t.wr = idx < 240;
}

__device__ __forceinline__ void writeI(char* smem, const IT &t) {
    if (!t.wr) return;
#pragma unroll
    for (int xi = 0; xi < 4; ++xi) {
        bf16x8 v;
#pragma unroll
        for (int q = 0; q < 8; ++q) v[q] = (__bf16)t.r[q][xi];
        mask16(v, t.m);
        *(bf16x8*)(smem + (t.sp + xi) * SSTR + t.ich * 16) = v;
    }
}

__device__ __forceinline__ void issueH(const float* __restrict__ xb, int z, int y0, int x0,
                                       int idx, HT &t) {
    int s = idx & 1, ich = (idx >> 1) & 1, row = idx >> 2;
    int ly = row % YL, lz = row / YL;
    int lx = s ? (XL - 1) : 0;
    int gz = z - 1 + lz, gy = y0 - 1 + ly, gx = x0 - 1 + lx;
    bool ok = ((unsigned)gz < (unsigned)Dm) && ((unsigned)gy < (unsigned)Dm) &&
              ((unsigned)gx < (unsigned)Dm);
    t.m = ok ? 0xFFFFFFFFu : 0u;
    int gzc = ok ? gz : 0, gyc = ok ? gy : 0, gxc = ok ? gx : 0;
    const float* g = xb + (long)(ich * 8) * PL + ((long)gzc * Dm + gyc) * Dm + gxc;
#pragma unroll
    for (int q = 0; q < 8; ++q) t.r[q] = g[(long)q * PL];
    t.sp = row * XL + lx;
    t.ich = ich;
    t.wr = idx < 120;
}

__device__ __forceinline__ void writeH(char* smem, const HT &t) {
    if (!t.wr) return;
    bf16x8 v;
#pragma unroll
    for (int q = 0; q < 8; ++q) v[q] = (__bf16)t.r[q];
    mask16(v, t.m);
    *(bf16x8*)(smem + t.sp * SSTR + t.ich * 16) = v;
}

__global__ __launch_bounds__(64, 2)
void conv_mfma_kernel(const float* __restrict__ x, const unsigned short* __restrict__ kwf,
                      const float* __restrict__ bias, float* __restrict__ out)
{
    __shared__ __align__(16) char smem[LDSB];

    const int NXT = Dm / XT, NYT = Dm / YT;            // 6, 12
    const int NUNITS = BSn * Dm * NYT * NXT;           // 27648
    int raw = blockIdx.x;
    int u = (raw & 7) * (NUNITS / 8) + (raw >> 3);     // XCD-contiguous chunks

    int tx = u % NXT; u /= NXT;
    int ty = u % NYT; u /= NYT;
    int z  = u % Dm;
    int b  = u / Dm;
    int x0 = tx * XT, y0 = ty * YT;

    int lane = threadIdx.x;
    const float* xb = x + (long)b * ICn * PL;

    // ---- A-fragment loads first (stay in flight through staging) ----
    const unsigned short* kwb = kwf + (long)b * FRAG_ELEMS;
    f32x4 afr[NG];
#pragma unroll
    for (int grp = 0; grp < NG; ++grp)
        afr[grp] = *(const f32x4*)(kwb + (grp * 64 + lane) * 8);

    // ---- staging: 2-deep pipelined, branchless loads, wave-private ----
    IT t0, t1, t2, t3;
    HT h0, h1;
    issueI(xb, z, y0, x0, lane,       t0);
    issueI(xb, z, y0, x0, 64 + lane,  t1);
    writeI(smem, t0);
    issueI(xb, z, y0, x0, 128 + lane, t2);
    writeI(smem, t1);
    issueI(xb, z, y0, x0, 192 + lane, t3);
    writeI(smem, t2);
    issueH(xb, z, y0, x0, lane,       h0);
    issueH(xb, z, y0, x0, 64 + lane,  h1);
    writeI(smem, t3);
    writeH(smem, h0);
    writeH(smem, h1);

    __syncthreads();    // single-wave block: just a waitcnt, no cross-wave stall

#pragma unroll
    for (int grp = 0; grp < NG; ++grp)
        asm volatile("" : "+v"(afr[grp]));   // keep resident, don't remat

    int n   = lane & 15;
    int hi  = lane >> 4;
    int cl  = hi >> 1;
    int ich = hi & 1;

    int addr_g[5];
#pragma unroll
    for (int g = 0; g < 5; ++g) {
        int c = 2 * g + cl;
        if (c > 8) c = 8;                    // pad combo -> safe addr (A is zero)
        addr_g[g] = n * SSTR + ich * 16 + coff(c);
    }

    f32x4 acc[YT];
#pragma unroll
    for (int yy = 0; yy < YT; ++yy) acc[yy] = (f32x4){0.f, 0.f, 0.f, 0.f};

    // 10 input y-planes feed 8 output rows; plane read once per combo-set
#pragma unroll
    for (int p = 0; p < YL; ++p) {
        bf16x8 F[5];
#pragma unroll
        for (int g = 0; g < 5; ++g)
            F[g] = *(const bf16x8*)(smem + addr_g[g] + p * (XL * SSTR));
#pragma unroll
        for (int tyk = 0; tyk < 3; ++tyk) {
            int yy = p - tyk;
            if (yy >= 0 && yy < YT) {
#pragma unroll
                for (int g = 0; g < 5; ++g)
                    acc[yy] = __builtin_amdgcn_mfma_f32_16x16x32_bf16(
                        __builtin_bit_cast(bf16x8, afr[tyk * 5 + g]), F[g], acc[yy], 0, 0, 0);
            }
        }
    }

    // epilogue
    float4 bv = *(const float4*)(bias + b * OCn + hi * 4);
#pragma unroll
    for (int yy = 0; yy < YT; ++yy) {
        int yo = y0 + yy;
        long obase = ((((long)b * OCn + hi * 4) * Dm + z) * Dm + yo) * Dm + x0 + n;
#pragma unroll
        for (int r = 0; r < 4; ++r)
            out[obase + (long)r * PL] = acc[yy][r] + ((const float*)&bv)[r];
    }
}

extern "C" void kernel_launch(void* const* d_in, const int* in_sizes, int n_in,
                              void* d_out, int out_size, void* d_ws, size_t ws_size,
                              hipStream_t stream)
{
    const float* x   = (const float*)d_in[0];
    const float* hyp = (const float*)d_in[1];
    const float* Wk  = (const float*)d_in[2];
    const float* bk  = (const float*)d_in[3];
    const float* Wb  = (const float*)d_in[4];
    const float* bb  = (const float*)d_in[5];
    float* out = (float*)d_out;

    unsigned short* kwf = (unsigned short*)d_ws;                        // 61440 B
    float* bias = (float*)((char*)d_ws + (size_t)BSn * FRAG_ELEMS * 2); // 64 floats

    hipLaunchKernelGGL(hyper_frag_kernel, dim3((BSn * FRAG_ELEMS) / 256), dim3(256), 0, stream,
                       hyp, Wk, bk, kwf);
    hipLaunchKernelGGL(hyper_bias_kernel, dim3(1), dim3(64), 0, stream,
                       hyp, Wb, bb, bias);

    const int NUNITS = BSn * Dm * (Dm / YT) * (Dm / XT);                // 27648
    hipLaunchKernelGGL(conv_mfma_kernel, dim3(NUNITS), dim3(64), 0, stream,
                       x, kwf, bias, out);
}

// Round 8
// 189.490 us; speedup vs baseline: 1.3424x; 1.3424x over previous
//
#include <hip/hip_runtime.h>

#define Dm 96
#define PL (Dm*Dm*Dm)               // 884736 elements per (b, ic) plane
#define ICn 16
#define OCn 16
#define HYPn 128
#define BSn 4
// K-packing: 15 groups of K=32. grp = ty*5 + g (ty = ky tap 0..2, g = 0..4).
// k_local = cl*16 + ic, cl in {0,1} -> (kz,kx) combo c = 2g+cl (c=9 is padding).
// Single ky per group => B-fragment depends only on the INPUT y-plane, shared
// across neighboring output rows.
#define NG 15
#define FRAG_ELEMS (NG*64*8)        // 7680 bf16 per sample

typedef float   f32x4  __attribute__((ext_vector_type(4)));
typedef __bf16  bf16x8 __attribute__((ext_vector_type(8)));

__device__ __forceinline__ unsigned short f2bf(float f) {
    unsigned u = __builtin_bit_cast(unsigned, f);
    u = (u + 0x7FFFu + ((u >> 16) & 1u)) >> 16;
    return (unsigned short)u;
}

// ---------------- hypernetwork: A-fragments in MFMA lane order ----------------
__global__ __launch_bounds__(256)
void hyper_frag_kernel(const float* __restrict__ hyp, const float* __restrict__ Wk,
                       const float* __restrict__ bk, unsigned short* __restrict__ kwf)
{
    int t = blockIdx.x * 256 + threadIdx.x;
    if (t >= BSn * FRAG_ELEMS) return;
    int j    = t & 7;
    int lane = (t >> 3) & 63;
    int rest = t >> 9;
    int grp  = rest % NG;
    int b    = rest / NG;
    int oc = lane & 15, hi = lane >> 4;
    int ty = grp / 5, g = grp % 5;
    int cl = hi >> 1;
    int ic = (hi & 1) * 8 + j;
    int c  = 2 * g + cl;
    float acc = 0.f;
    if (c < 9) {
        int tz = c / 3, tx = c % 3;
        int r = (oc * ICn + ic) * 27 + (tz * 9 + ty * 3 + tx);
        const float4* w = (const float4*)(Wk + (long)r * HYPn);
        const float4* h = (const float4*)(hyp + (long)b * HYPn);
        acc = bk[r];
#pragma unroll
        for (int q = 0; q < HYPn / 4; ++q) {
            float4 a = h[q], cc = w[q];
            acc += a.x * cc.x + a.y * cc.y + a.z * cc.z + a.w * cc.w;
        }
    }
    kwf[t] = f2bf(acc);
}

__global__ __launch_bounds__(64)
void hyper_bias_kernel(const float* __restrict__ hyp, const float* __restrict__ Wb,
                       const float* __restrict__ bb, float* __restrict__ bias)
{
    int t = threadIdx.x;          // 64 = 4 samples * 16 oc
    int b = t >> 4, oc = t & 15;
    const float4* w = (const float4*)(Wb + (long)oc * HYPn);
    const float4* h = (const float4*)(hyp + (long)b * HYPn);
    float acc = bb[oc];
#pragma unroll
    for (int q = 0; q < HYPn / 4; ++q) {
        float4 a = h[q], c = w[q];
        acc += a.x * c.x + a.y * c.y + a.z * c.z + a.w * c.w;
    }
    bias[t] = acc;                // [b][oc]
}

// ---------------- MFMA implicit-GEMM conv: double-buffered z-tile pipeline ---
// Block = 256 thr (4 waves, wave = z-row). Persistent over NT=4 z-tiles.
// Per step: issue next tile's global loads (regs) -> compute current tile from
// LDS buf[t&1] -> write next into buf[(t+1)&1] -> ONE barrier. Stage latency
// hides under 480 MFMAs of compute.
#define ZT 4
#define YT 8
#define XT 16
#define ZL 6
#define YL 10
#define XL 18
#define SPN (ZL*YL*XL)              // 1080 spatial points
#define SSTR 32
#define LDSB (SPN*SSTR)             // 34560 bytes per buffer
#define NT 4                        // z-tiles per block
#define ZCH (ZT*NT)                 // 16 z per block

__device__ constexpr int coff(int c) {   // (kz,kx) combo byte offset
    return ((c / 3) * YL * XL + (c % 3)) * SSTR;
}

__device__ __forceinline__ void mask16(bf16x8 &v, unsigned m) {
    uint4 u = __builtin_bit_cast(uint4, v);
    u.x &= m; u.y &= m; u.z &= m; u.w &= m;
    v = __builtin_bit_cast(bf16x8, u);
}

struct Stage {
    f32x4 ir[2][8];                 // interior: 2 rounds x 8 ic-planes (float4 = 4 x)
    unsigned im[2];
    int isp[2], iich[2];
    bool iact[2];
    float hr[8];                    // halo: 1 round x 8 ic-planes (scalar)
    unsigned hm;
    int hsp, hich;
    bool hact;
};

__device__ __forceinline__ void stage_issue(const float* __restrict__ xb,
                                            int ztile, int y0, int x0, int tid, Stage &S)
{
    // interior: 480 quad-tasks = 4 x-quads * 2 ic-halves * 60 rows
#pragma unroll
    for (int r = 0; r < 2; ++r) {
        int idx = tid + 256 * r;
        bool act = idx < 480;
        int xq = idx & 3, ich = (idx >> 2) & 1, row = idx >> 3;
        if (row > 59) row = 59;                         // clamp inactive
        int ly = row % YL, lz = row / YL;
        int gz = ztile - 1 + lz, gy = y0 - 1 + ly;
        bool ok = act && (unsigned)gz < (unsigned)Dm && (unsigned)gy < (unsigned)Dm;
        S.im[r] = ok ? 0xFFFFFFFFu : 0u;
        int gzc = ok ? gz : 0, gyc = ok ? gy : 0;
        const float* g = xb + (long)(ich * 8) * PL + ((long)gzc * Dm + gyc) * Dm + (x0 + 4 * xq);
#pragma unroll
        for (int q = 0; q < 8; ++q) S.ir[r][q] = *(const f32x4*)(g + (long)q * PL);
        S.isp[r]  = row * XL + 1 + 4 * xq;
        S.iich[r] = ich;
        S.iact[r] = act;
    }
    // halo: 240 tasks = 2 sides * 2 ic-halves * 60 rows
    {
        int idx = tid;
        bool act = idx < 240;
        int s = idx & 1, ich = (idx >> 1) & 1, row = idx >> 2;
        if (row > 59) row = 59;
        int ly = row % YL, lz = row / YL;
        int lx = s ? (XL - 1) : 0;
        int gz = ztile - 1 + lz, gy = y0 - 1 + ly, gx = x0 - 1 + lx;
        bool ok = act && (unsigned)gz < (unsigned)Dm && (unsigned)gy < (unsigned)Dm &&
                  (unsigned)gx < (unsigned)Dm;
        S.hm = ok ? 0xFFFFFFFFu : 0u;
        int gzc = ok ? gz : 0, gyc = ok ? gy : 0, gxc = ok ? gx : 0;
        const float* g = xb + (long)(ich * 8) * PL + ((long)gzc * Dm + gyc) * Dm + gxc;
#pragma unroll
        for (int q = 0; q < 8; ++q) S.hr[q] = g[(long)q * PL];
        S.hsp  = row * XL + lx;
        S.hich = ich;
        S.hact = act;
    }
}

__device__ __forceinline__ void stage_write(char* buf, const Stage &S)
{
#pragma unroll
    for (int r = 0; r < 2; ++r) {
        if (S.iact[r]) {
#pragma unroll
            for (int xi = 0; xi < 4; ++xi) {
                bf16x8 v;
#pragma unroll
                for (int q = 0; q < 8; ++q) v[q] = (__bf16)S.ir[r][q][xi];
                mask16(v, S.im[r]);
                *(bf16x8*)(buf + (S.isp[r] + xi) * SSTR + S.iich[r] * 16) = v;
            }
        }
    }
    if (S.hact) {
        bf16x8 v;
#pragma unroll
        for (int q = 0; q < 8; ++q) v[q] = (__bf16)S.hr[q];
        mask16(v, S.hm);
        *(bf16x8*)(buf + S.hsp * SSTR + S.hich * 16) = v;
    }
}

__global__ __launch_bounds__(256, 2)
void conv_mfma_kernel(const float* __restrict__ x, const unsigned short* __restrict__ kwf,
                      const float* __restrict__ bias, float* __restrict__ out)
{
    __shared__ __align__(16) char smem[2 * LDSB];

    const int NXT = Dm / XT, NYT = Dm / YT, NZC = Dm / ZCH;   // 6, 12, 6
    const int NB  = BSn * NZC * NYT * NXT;                    // 1728
    int raw = blockIdx.x;
    int u = (raw & 7) * (NB / 8) + (raw >> 3);                // XCD-contiguous

    int tx = u % NXT; u /= NXT;
    int ty = u % NYT; u /= NYT;
    int zc = u % NZC;
    int b  = u / NZC;
    int x0 = tx * XT, y0 = ty * YT, zbase = zc * ZCH;

    int tid  = threadIdx.x;
    int lane = tid & 63;
    int wz   = tid >> 6;                 // wave -> z-row within tile

    const float* xb = x + (long)b * ICn * PL;

    // ---- A fragments: load once, pin ----
    const unsigned short* kwb = kwf + (long)b * FRAG_ELEMS;
    f32x4 afr[NG];
#pragma unroll
    for (int grp = 0; grp < NG; ++grp) {
        afr[grp] = *(const f32x4*)(kwb + (grp * 64 + lane) * 8);
        asm volatile("" : "+v"(afr[grp]));
    }

    int n   = lane & 15;
    int hi  = lane >> 4;
    int cl  = hi >> 1;
    int ich = hi & 1;

    int addr_g[5];
#pragma unroll
    for (int g = 0; g < 5; ++g) {
        int c = 2 * g + cl;
        if (c > 8) c = 8;                // pad combo -> safe addr (A is zero)
        addr_g[g] = ((wz * YL) * XL + n) * SSTR + ich * 16 + coff(c);
    }

    float4 bv = *(const float4*)(bias + b * OCn + hi * 4);

    // ---- prologue: stage tile 0 into buf0 ----
    {
        Stage S;
        stage_issue(xb, zbase, y0, x0, tid, S);
        stage_write(smem, S);
    }
    __syncthreads();

    // ---- pipelined main loop over NT z-tiles ----
#pragma unroll
    for (int t = 0; t < NT; ++t) {
        char* cur = smem + (t & 1) * LDSB;
        char* nxt = smem + ((t + 1) & 1) * LDSB;
        int ztile = zbase + t * ZT;

        Stage S;
        if (t < NT - 1)
            stage_issue(xb, ztile + ZT, y0, x0, tid, S);   // loads in flight

        // compute current tile
        f32x4 acc[YT];
#pragma unroll
        for (int yy = 0; yy < YT; ++yy) acc[yy] = (f32x4){0.f, 0.f, 0.f, 0.f};
#pragma unroll
        for (int p = 0; p < YL; ++p) {
            bf16x8 F[5];
#pragma unroll
            for (int g = 0; g < 5; ++g)
                F[g] = *(const bf16x8*)(cur + addr_g[g] + p * (XL * SSTR));
#pragma unroll
            for (int tyk = 0; tyk < 3; ++tyk) {
                int yy = p - tyk;
                if (yy >= 0 && yy < YT) {
#pragma unroll
                    for (int g = 0; g < 5; ++g)
                        acc[yy] = __builtin_amdgcn_mfma_f32_16x16x32_bf16(
                            __builtin_bit_cast(bf16x8, afr[tyk * 5 + g]), F[g], acc[yy], 0, 0, 0);
                }
            }
        }

        // epilogue for this tile
        int zo = ztile + wz;
#pragma unroll
        for (int yy = 0; yy < YT; ++yy) {
            int yo = y0 + yy;
            long obase = ((((long)b * OCn + hi * 4) * Dm + zo) * Dm + yo) * Dm + x0 + n;
#pragma unroll
            for (int r = 0; r < 4; ++r)
                out[obase + (long)r * PL] = acc[yy][r] + ((const float*)&bv)[r];
        }

        if (t < NT - 1) {
            __builtin_amdgcn_sched_barrier(0);   // keep write AFTER compute
            stage_write(nxt, S);
            __syncthreads();
        }
    }
}

extern "C" void kernel_launch(void* const* d_in, const int* in_sizes, int n_in,
                              void* d_out, int out_size, void* d_ws, size_t ws_size,
                              hipStream_t stream)
{
    const float* x   = (const float*)d_in[0];
    const float* hyp = (const float*)d_in[1];
    const float* Wk  = (const float*)d_in[2];
    const float* bk  = (const float*)d_in[3];
    const float* Wb  = (const float*)d_in[4];
    const float* bb  = (const float*)d_in[5];
    float* out = (float*)d_out;

    unsigned short* kwf = (unsigned short*)d_ws;                        // 61440 B
    float* bias = (float*)((char*)d_ws + (size_t)BSn * FRAG_ELEMS * 2); // 64 floats

    hipLaunchKernelGGL(hyper_frag_kernel, dim3((BSn * FRAG_ELEMS) / 256), dim3(256), 0, stream,
                       hyp, Wk, bk, kwf);
    hipLaunchKernelGGL(hyper_bias_kernel, dim3(1), dim3(64), 0, stream,
                       hyp, Wb, bb, bias);

    const int NB = BSn * (Dm / ZCH) * (Dm / YT) * (Dm / XT);            // 1728
    hipLaunchKernelGGL(conv_mfma_kernel, dim3(NB), dim3(256), 0, stream,
                       x, kwf, bias, out);
}